// Round 8
// baseline (860.930 us; speedup 1.0000x reference)
//
#include <hip/hip_runtime.h>
#include <hip/hip_bf16.h>
#include <math.h>

#define Bsz 4
#define Tsz 2048
#define Csz 1024
#define Hsz 16
#define Dsz 64
#define Msz (Bsz * Tsz)   // 8192 rows

typedef __attribute__((ext_vector_type(8))) __bf16 bf16x8;
typedef __attribute__((ext_vector_type(2))) __bf16 bf16x2;
typedef __attribute__((ext_vector_type(4))) float f32x4;

#define GLOBAL_AS __attribute__((address_space(1)))
#define LDS_AS    __attribute__((address_space(3)))

#if __has_builtin(__builtin_amdgcn_exp2f)
#define EXP2F(x) __builtin_amdgcn_exp2f(x)
#define HAVE_NATIVE_EXP2 1
#else
#define HAVE_NATIVE_EXP2 0
#endif

// ---------------- block-wide reductions (256 threads = 4 waves of 64) -------

__device__ __forceinline__ float block_sum256(float v, float* sh) {
#pragma unroll
    for (int o = 32; o > 0; o >>= 1) v += __shfl_down(v, o, 64);
    int lane = threadIdx.x & 63, w = threadIdx.x >> 6;
    __syncthreads();
    if (lane == 0) sh[w] = v;
    __syncthreads();
    return sh[0] + sh[1] + sh[2] + sh[3];
}

// ---------------- LayerNorm -> bf16: one block per row, C=1024 --------------

__global__ __launch_bounds__(256) void layernorm_bf16(const float* __restrict__ x,
                                                      const float* __restrict__ g,
                                                      const float* __restrict__ b,
                                                      __bf16* __restrict__ out) {
    __shared__ float sh[4];
    const int row = blockIdx.x;
    const float* xr = x + (size_t)row * Csz;
    float v[4];
    float s = 0.f, ss = 0.f;
#pragma unroll
    for (int i = 0; i < 4; i++) {
        v[i] = xr[threadIdx.x + i * 256];
        s += v[i];
        ss += v[i] * v[i];
    }
    float tot = block_sum256(s, sh);
    float mean = tot * (1.0f / Csz);
    float tot2 = block_sum256(ss, sh);
    float var = tot2 * (1.0f / Csz) - mean * mean;
    float inv = rsqrtf(var + 1e-5f);
    __bf16* orow = out + (size_t)row * Csz;
#pragma unroll
    for (int i = 0; i < 4; i++) {
        int c = threadIdx.x + i * 256;
        orow[c] = (__bf16)((v[i] - mean) * inv * g[c] + b[c]);
    }
}

// ---------------- weight transpose + bf16 cast: W(KxN) f32 -> Wt(NxK) bf16 --

__global__ __launch_bounds__(256) void transpose_bf16(const float* __restrict__ W,
                                                      __bf16* __restrict__ Wt,
                                                      int K, int N) {
    __shared__ float t[32][33];
    const int k0 = blockIdx.y * 32, n0 = blockIdx.x * 32;
    const int c = threadIdx.x & 31, r8 = threadIdx.x >> 5;
#pragma unroll
    for (int it = 0; it < 4; it++) {
        int r = r8 + it * 8;
        t[r][c] = W[(size_t)(k0 + r) * N + n0 + c];
    }
    __syncthreads();
#pragma unroll
    for (int it = 0; it < 4; it++) {
        int r = r8 + it * 8;  // n-offset
        Wt[(size_t)(n0 + r) * K + k0 + c] = (__bf16)t[c][r];
    }
}

// batched version for the four 1024x1024 weights (one launch)
__global__ __launch_bounds__(256) void transpose4_bf16(const float* __restrict__ Wa,
                                                       const float* __restrict__ Wb,
                                                       const float* __restrict__ Wc,
                                                       const float* __restrict__ Wd,
                                                       __bf16* __restrict__ Ta,
                                                       __bf16* __restrict__ Tb,
                                                       __bf16* __restrict__ Tc,
                                                       __bf16* __restrict__ Td) {
    __shared__ float t[32][33];
    const float* W = (blockIdx.z == 0) ? Wa : (blockIdx.z == 1) ? Wb : (blockIdx.z == 2) ? Wc : Wd;
    __bf16* Wt = (blockIdx.z == 0) ? Ta : (blockIdx.z == 1) ? Tb : (blockIdx.z == 2) ? Tc : Td;
    const int k0 = blockIdx.y * 32, n0 = blockIdx.x * 32;
    const int c = threadIdx.x & 31, r8 = threadIdx.x >> 5;
#pragma unroll
    for (int it = 0; it < 4; it++) {
        int r = r8 + it * 8;
        t[r][c] = W[(size_t)(k0 + r) * Csz + n0 + c];
    }
    __syncthreads();
#pragma unroll
    for (int it = 0; it < 4; it++) {
        int r = r8 + it * 8;
        Wt[(size_t)(n0 + r) * Csz + k0 + c] = (__bf16)t[c][r];
    }
}

// ---------------- 128x128 bf16 MFMA GEMM (kept for proj: N=1024) ------------

__global__ __launch_bounds__(256) void gemm_bf16(const __bf16* __restrict__ A,
                                                 const __bf16* __restrict__ Bt,
                                                 float* __restrict__ Cf,
                                                 float* __restrict__ Cf2,
                                                 __bf16* __restrict__ Cb,
                                                 int M, int N, int K, int ld,
                                                 const float* __restrict__ bias,
                                                 const float* __restrict__ resid,
                                                 int do_relu) {
    __shared__ __bf16 As[128 * 64];   // 16 KB
    __shared__ __bf16 Bs[128 * 64];   // 16 KB

    const int tid = threadIdx.x;
    const int lane = tid & 63;
    const int w = tid >> 6;

    const int nwg = (int)(gridDim.x * gridDim.y);
    const int did = (int)(blockIdx.y * gridDim.x + blockIdx.x);
    const int work = ((nwg & 7) == 0) ? ((did & 7) * (nwg >> 3) + (did >> 3)) : did;
    const int bx = work % (int)gridDim.x;
    const int by = work / (int)gridDim.x;

    const int rowBase = by * 128;
    const int colBase = bx * 128;
    const int wr = (w & 1) * 64;
    const int wc = (w >> 1) * 64;

    const __bf16* Ak = A + (size_t)blockIdx.z * K;
    const __bf16* Bk = Bt + (size_t)blockIdx.z * K;
    float* Cfu = Cf;
    const float* residu = resid;
    const float* biasu = bias;
    if (blockIdx.z == 1) { Cfu = Cf2; residu = nullptr; biasu = nullptr; }

    const int m16 = lane & 15;
    const int kg = lane >> 4;
    const int swz = m16 & 7;

    const int sr = lane >> 3;     // row within 8-row group
    const int sc = lane & 7;      // LDS chunk slot
    const int gcs = sc ^ sr;      // fetched global chunk (swizzle key row&7)

    f32x4 acc[4][4] = {};

    for (int k0 = 0; k0 < K; k0 += 64) {
        __syncthreads();  // prior-iter LDS reads complete
#pragma unroll
        for (int it = 0; it < 4; it++) {
            int lr = w * 32 + it * 8;
            const __bf16* ga = Ak + (size_t)(rowBase + lr + sr) * ld + k0 + gcs * 8;
            __builtin_amdgcn_global_load_lds((const GLOBAL_AS unsigned int*)ga,
                                             (LDS_AS unsigned int*)(As + lr * 64),
                                             16, 0, 0);
            const __bf16* gb = Bk + (size_t)(colBase + lr + sr) * ld + k0 + gcs * 8;
            __builtin_amdgcn_global_load_lds((const GLOBAL_AS unsigned int*)gb,
                                             (LDS_AS unsigned int*)(Bs + lr * 64),
                                             16, 0, 0);
        }
        __syncthreads();  // drains vmcnt -> tiles visible

#pragma unroll
        for (int s = 0; s < 2; s++) {
            const int slot = ((s * 4 + kg) ^ swz) * 8;
            bf16x8 af[4], bfv[4];
#pragma unroll
            for (int i = 0; i < 4; i++)
                af[i] = *(const bf16x8*)(As + (wr + i * 16 + m16) * 64 + slot);
#pragma unroll
            for (int j = 0; j < 4; j++)
                bfv[j] = *(const bf16x8*)(Bs + (wc + j * 16 + m16) * 64 + slot);
#pragma unroll
            for (int i = 0; i < 4; i++)
#pragma unroll
                for (int j = 0; j < 4; j++)
                    acc[i][j] = __builtin_amdgcn_mfma_f32_16x16x32_bf16(af[i], bfv[j], acc[i][j], 0, 0, 0);
        }
    }

    const int cn = lane & 15;
    const int rq = (lane >> 4) * 4;
    float bj[4];
#pragma unroll
    for (int j = 0; j < 4; j++)
        bj[j] = biasu ? biasu[colBase + wc + j * 16 + cn] : 0.f;

#pragma unroll
    for (int i = 0; i < 4; i++) {
#pragma unroll
        for (int r = 0; r < 4; r++) {
            int m = rowBase + wr + i * 16 + rq + r;
            size_t rowOff = (size_t)m * N;
#pragma unroll
            for (int j = 0; j < 4; j++) {
                int n = colBase + wc + j * 16 + cn;
                float v = acc[i][j][r] + bj[j];
                if (do_relu) v = fmaxf(v, 0.f);
                if (residu) v += residu[rowOff + n];
                if (Cfu) Cfu[rowOff + n] = v;
                if (Cb && blockIdx.z == 0) Cb[rowOff + n] = (__bf16)v;
            }
        }
    }
}

// ---------------- 256x256 8-phase bf16 MFMA GEMM (T3+T4 + frag prefetch) ----
// Stage-slot ledger IDENTICAL to the round-2 schedule (measured 100.4 us):
//   ph1:(t0+1)A0  ph2:(t0+1)B1  ph3:(t0+1)A1  ph4:(t0+2)B0 +vmcnt(2)
//   ph5:(t0+2)A0  ph6:(t0+2)B1  ph7:(t0+2)A1  ph8:(t0+3)B0 +vmcnt(2)
// Fragment register-prefetch one phase ahead (see r6 comment for the hazard
// audit). ROUND-7 LESSON: __launch_bounds__(512,2) made the compiler target a
// 128-VGPR budget; the +64-VGPR frag set spilled to scratch (WRITE_SIZE
// 67->251 MB, dur 100->212 us). LDS=128KB already limits residency to 1
// block/CU = 2 waves/SIMD, which the HW sustains up to 256 VGPR - so bound
// (512,1) and let the allocator use ~220 regs with NO occupancy change.

#define Tile256 (256 * 64)

#define STAGE_A6(kt, hh) do {                                                      \
    const int bbuf_ = (kt) & 1;                                                    \
    _Pragma("unroll") for (int l_ = 0; l_ < 2; l_++) {                             \
        const int lr_ = (hh) * 128 + w * 16 + l_ * 8;                              \
        const __bf16* ga_ = Ak + (size_t)(rowBase + lr_ + sr) * ld + (kt) * 64 + gcs * 8; \
        __builtin_amdgcn_global_load_lds((const GLOBAL_AS unsigned int*)ga_,       \
            (LDS_AS unsigned int*)(As + bbuf_ * Tile256 + lr_ * 64), 16, 0, 0);    \
    } } while (0)

#define STAGE_B6(kt, hh) do {                                                      \
    const int bbuf_ = (kt) & 1;                                                    \
    _Pragma("unroll") for (int l_ = 0; l_ < 2; l_++) {                             \
        const int lr_ = (hh) * 128 + w * 16 + l_ * 8;                              \
        const __bf16* gb_ = Bk + (size_t)(colBase + lr_ + sr) * ld + (kt) * 64 + gcs * 8; \
        __builtin_amdgcn_global_load_lds((const GLOBAL_AS unsigned int*)gb_,       \
            (LDS_AS unsigned int*)(Bs + bbuf_ * Tile256 + lr_ * 64), 16, 0, 0);    \
    } } while (0)

// bufc/ksc/qc/FA: current phase's buffer, k-slice, C-quadrant, frag set.
// bufn/ksn/qn/FN: next phase's. DORD: issue next-phase reads (false only at
// the very last phase of the kernel).
#define PH7(bufc, ksc, qc, FA, bufn, ksn, qn, FN, DORD, STAGES, VMW) do {          \
    STAGES;                                                                        \
    VMW;                                                                           \
    __builtin_amdgcn_s_barrier();                                                  \
    if (DORD) {                                                                    \
        _Pragma("unroll") for (int i_ = 0; i_ < 4; i_++)                           \
            af[FN][i_] = *(const bf16x8*)(As + (bufn) * Tile256 +                  \
                  (wm * 128 + ((qn) * 4 + i_) * 16 + m16) * 64 +                   \
                  ((((ksn) * 4 + kg) ^ swz) * 8));                                 \
        if ((qn) == 0) {                                                           \
            _Pragma("unroll") for (int j_ = 0; j_ < 4; j_++)                       \
                bv[ksn][j_] = *(const bf16x8*)(Bs + (bufn) * Tile256 +             \
                      (wn * 64 + j_ * 16 + m16) * 64 +                             \
                      ((((ksn) * 4 + kg) ^ swz) * 8));                             \
        }                                                                          \
    }                                                                              \
    __builtin_amdgcn_s_setprio(1);                                                 \
    _Pragma("unroll") for (int i_ = 0; i_ < 4; i_++)                               \
        _Pragma("unroll") for (int j_ = 0; j_ < 4; j_++)                           \
            acc[(qc) * 4 + i_][j_] = __builtin_amdgcn_mfma_f32_16x16x32_bf16(      \
                af[FA][i_], bv[ksc][j_], acc[(qc) * 4 + i_][j_], 0, 0, 0);         \
    __builtin_amdgcn_s_setprio(0);                                                 \
    __builtin_amdgcn_s_barrier();                                                  \
} while (0)

__global__ __launch_bounds__(512, 1) void gemm256(const __bf16* __restrict__ A,
                                                  const __bf16* __restrict__ Bt,
                                                  float* __restrict__ Cf,
                                                  float* __restrict__ Cf2,
                                                  __bf16* __restrict__ Cb,
                                                  int M, int N, int K, int ld,
                                                  const float* __restrict__ bias,
                                                  const float* __restrict__ resid,
                                                  int do_relu) {
    __shared__ __bf16 As[2 * Tile256];  // 64 KB
    __shared__ __bf16 Bs[2 * Tile256];  // 64 KB

    const int tid = threadIdx.x;
    const int lane = tid & 63;
    const int w = tid >> 6;        // wave 0..7
    const int wm = w >> 2;         // 0..1 (M half)
    const int wn = w & 3;          // 0..3 (N quarter)

    const int nwg = (int)(gridDim.x * gridDim.y);
    const int did = (int)(blockIdx.y * gridDim.x + blockIdx.x);
    const int work = ((nwg & 7) == 0) ? ((did & 7) * (nwg >> 3) + (did >> 3)) : did;
    const int bx = work % (int)gridDim.x;
    const int by = work / (int)gridDim.x;
    const int rowBase = by * 256;
    const int colBase = bx * 256;

    const __bf16* Ak = A + (size_t)blockIdx.z * K;
    const __bf16* Bk = Bt + (size_t)blockIdx.z * K;
    float* Cfu = Cf;
    const float* residu = resid;
    const float* biasu = bias;
    if (blockIdx.z == 1) { Cfu = Cf2; residu = nullptr; biasu = nullptr; }

    const int m16 = lane & 15;
    const int kg = lane >> 4;
    const int swz = m16 & 7;
    const int sr = lane >> 3;
    const int sc = lane & 7;
    const int gcs = sc ^ sr;

    const int nt = K >> 6;  // K-tiles of 64 -- must be even, >= 4

    f32x4 acc[8][4] = {};
    bf16x8 af[2][4];
    bf16x8 bv[2][4];

    // prologue: T0 {A0,B0,A1,B1}, then T1 B0; keep T1B0 in flight
    STAGE_A6(0, 0); STAGE_B6(0, 0); STAGE_A6(0, 1); STAGE_B6(0, 1);
    STAGE_B6(1, 0);
    asm volatile("s_waitcnt vmcnt(2)" ::: "memory");
    __builtin_amdgcn_s_barrier();
    // preload ph1 fragments (buf0, ks0, q0) into af[0] / bv[0]
#pragma unroll
    for (int i = 0; i < 4; i++)
        af[0][i] = *(const bf16x8*)(As + (wm * 128 + i * 16 + m16) * 64 + ((kg ^ swz) * 8));
#pragma unroll
    for (int j = 0; j < 4; j++)
        bv[0][j] = *(const bf16x8*)(Bs + (wn * 64 + j * 16 + m16) * 64 + ((kg ^ swz) * 8));

    for (int t0 = 0; t0 < nt; t0 += 2) {
        const bool p2 = (t0 + 2 < nt);
        const bool p3 = (t0 + 3 < nt);
        PH7(0, 0, 0, 0,  0, 0, 1, 1, true, STAGE_A6(t0 + 1, 0), );
        PH7(0, 0, 1, 1,  0, 1, 0, 0, true, STAGE_B6(t0 + 1, 1), );
        PH7(0, 1, 0, 0,  0, 1, 1, 1, true, STAGE_A6(t0 + 1, 1), );
        PH7(0, 1, 1, 1,  1, 0, 0, 0, true, if (p2) STAGE_B6(t0 + 2, 0),
            if (p2) asm volatile("s_waitcnt vmcnt(2)" ::: "memory");
            else    asm volatile("s_waitcnt vmcnt(0)" ::: "memory"));
        PH7(1, 0, 0, 0,  1, 0, 1, 1, true, if (p2) STAGE_A6(t0 + 2, 0), );
        PH7(1, 0, 1, 1,  1, 1, 0, 0, true, if (p2) STAGE_B6(t0 + 2, 1), );
        PH7(1, 1, 0, 0,  1, 1, 1, 1, true, if (p2) STAGE_A6(t0 + 2, 1), );
        PH7(1, 1, 1, 1,  0, 0, 0, 0, p2,   if (p3) STAGE_B6(t0 + 3, 0),
            if (p3) asm volatile("s_waitcnt vmcnt(2)" ::: "memory");
            else    asm volatile("s_waitcnt vmcnt(0)" ::: "memory"));
    }

    // epilogue: C/D layout col=lane&15, row=(lane>>4)*4+reg
    const int cn = lane & 15;
    const int rqe = (lane >> 4) * 4;
    float bj[4];
#pragma unroll
    for (int j = 0; j < 4; j++)
        bj[j] = biasu ? biasu[colBase + wn * 64 + j * 16 + cn] : 0.f;

#pragma unroll
    for (int mi = 0; mi < 8; mi++) {
#pragma unroll
        for (int r = 0; r < 4; r++) {
            const int m = rowBase + wm * 128 + mi * 16 + rqe + r;
            const size_t rowOff = (size_t)m * N;
#pragma unroll
            for (int j = 0; j < 4; j++) {
                const int n = colBase + wn * 64 + j * 16 + cn;
                float v = acc[mi][j][r] + bj[j];
                if (do_relu) v = fmaxf(v, 0.f);
                if (residu) v += residu[rowOff + n];
                if (Cfu) Cfu[rowOff + n] = v;
                if (Cb && blockIdx.z == 0) Cb[rowOff + n] = (__bf16)v;
            }
        }
    }
}

// ---------------- split-K tail: out += p + b2 --------------------------------

__global__ __launch_bounds__(256) void add_partial(float* __restrict__ out,
                                                   const float* __restrict__ p,
                                                   const float* __restrict__ b2) {
    size_t i = ((size_t)blockIdx.x * 256 + threadIdx.x) * 4;
    float4 o = *(float4*)(out + i);
    const float4 a = *(const float4*)(p + i);
    const float4 bb = *(const float4*)(b2 + (i & (Csz - 1)));
    o.x += a.x + bb.x;
    o.y += a.y + bb.y;
    o.z += a.z + bb.z;
    o.w += a.w + bb.w;
    *(float4*)(out + i) = o;
}

// ---------------- MFMA flash attention, static-shift softmax ----------------
// Known-good pipelined version: K-tile kt+1 staged via global_load_lds (zero
// VGPR cost) + V-regs prefetched; raw s_barrier + counted vmcnt(4).

__global__ __launch_bounds__(256, 3) void attn_mfma(const __bf16* __restrict__ QKV,
                                                    __bf16* __restrict__ O) {
    __shared__ __bf16 Ks[2][64 * 64];  // double-buffered, 16 KB
    __shared__ __bf16 Vt[64 * 72];     // Vt[d][key], padded, 9 KB
    __shared__ __bf16 Ps[128 * 72];    // P[q][key], padded, 18 KB -> 43 KB total

    const int tid = threadIdx.x;
    const int lane = tid & 63;
    const int w = tid >> 6;
    const int bh = blockIdx.x;            // 0..63
    const int b = bh >> 4, h = bh & 15;
    const int qt = (int)gridDim.y - 1 - (int)blockIdx.y;  // heavy tiles first
    const int qbase = qt * 128;
    const int ld3C = 3 * Csz;

    const __bf16* Qg = QKV + (size_t)(b * Tsz) * ld3C + h * Dsz;
    const __bf16* Kg = Qg + Csz;
    const __bf16* Vg = Qg + 2 * Csz;

    const int m16 = lane & 15;
    const int kg = lane >> 4;
    const int rq = kg * 4;
    const int wrow = w * 32;
    const int swz = m16 & 7;

    bf16x8 aq[2][2];
#pragma unroll
    for (int i = 0; i < 2; i++)
#pragma unroll
        for (int s = 0; s < 2; s++)
            aq[i][s] = *(const bf16x8*)(Qg + (size_t)(qbase + wrow + i * 16 + m16) * ld3C + (s * 4 + kg) * 8);

    const int sr = lane >> 3;
    const int sc = lane & 7;
    const int gcs = sc ^ sr;

    const int kp = (lane & 31) * 2;
    const int dg = w * 2 + (lane >> 5);

    f32x4 Oacc[2][4];
    float l_part[2][4];
#pragma unroll
    for (int i = 0; i < 2; i++)
#pragma unroll
        for (int j = 0; j < 4; j++) Oacc[i][j] = (f32x4){0.f, 0.f, 0.f, 0.f};
#pragma unroll
    for (int i = 0; i < 2; i++)
#pragma unroll
        for (int r = 0; r < 4; r++) l_part[i][r] = 0.f;

    const float CEXP = 0.18033688f;  // 0.125 * log2(e)
    const int nkt = 2 * qt + 2;

    // ---- prologue: stage kt=0 K-tile + V regs (4 vmem ops in flight) ----
#pragma unroll
    for (int it = 0; it < 2; it++) {
        int lr = w * 16 + it * 8 + sr;
        const __bf16* src = Kg + (size_t)lr * ld3C + gcs * 8;
        __builtin_amdgcn_global_load_lds((const GLOBAL_AS unsigned int*)src,
                                         (LDS_AS unsigned int*)(&Ks[0][(w * 16 + it * 8) * 64]),
                                         16, 0, 0);
    }
    bf16x8 vc0 = *(const bf16x8*)(Vg + (size_t)kp * ld3C + dg * 8);
    bf16x8 vc1 = *(const bf16x8*)(Vg + (size_t)(kp + 1) * ld3C + dg * 8);
    bf16x8 vn0, vn1;

    for (int kt = 0; kt < nkt; kt++) {
        const int cur = kt & 1;
        const int kbase = kt * 64;

        // ---- prefetch kt+1 (K -> Ks[cur^1], V -> regs), then counted wait ----
        if (kt + 1 < nkt) {
            const int nb = kbase + 64;
#pragma unroll
            for (int it = 0; it < 2; it++) {
                int lr = w * 16 + it * 8 + sr;
                const __bf16* src = Kg + (size_t)(nb + lr) * ld3C + gcs * 8;
                __builtin_amdgcn_global_load_lds((const GLOBAL_AS unsigned int*)src,
                                                 (LDS_AS unsigned int*)(&Ks[cur ^ 1][(w * 16 + it * 8) * 64]),
                                                 16, 0, 0);
            }
            vn0 = *(const bf16x8*)(Vg + (size_t)(nb + kp) * ld3C + dg * 8);
            vn1 = *(const bf16x8*)(Vg + (size_t)(nb + kp + 1) * ld3C + dg * 8);
            asm volatile("s_waitcnt vmcnt(4)" ::: "memory");
        } else {
            asm volatile("s_waitcnt vmcnt(0)" ::: "memory");
        }
        __builtin_amdgcn_s_barrier();   // barrier1: Ks[cur] + vc fully landed

        // ---- QK^T ----
        f32x4 S[2][4];
#pragma unroll
        for (int i = 0; i < 2; i++)
#pragma unroll
            for (int j = 0; j < 4; j++) S[i][j] = (f32x4){0.f, 0.f, 0.f, 0.f};
#pragma unroll
        for (int s = 0; s < 2; s++) {
            bf16x8 bk[4];
#pragma unroll
            for (int j = 0; j < 4; j++)
                bk[j] = *(const bf16x8*)(&Ks[cur][(j * 16 + m16) * 64 + (((s * 4 + kg) ^ swz) * 8)]);
            __builtin_amdgcn_s_setprio(1);
#pragma unroll
            for (int i = 0; i < 2; i++)
#pragma unroll
                for (int j = 0; j < 4; j++)
                    S[i][j] = __builtin_amdgcn_mfma_f32_16x16x32_bf16(aq[i][s], bk[j], S[i][j], 0, 0, 0);
            __builtin_amdgcn_s_setprio(0);
        }

        // ---- softmax (uniform branch: mask only on last two tiles) ----
        if (kt >= 2 * qt) {
#pragma unroll
            for (int i = 0; i < 2; i++)
#pragma unroll
                for (int j = 0; j < 4; j++)
#pragma unroll
                    for (int r = 0; r < 4; r++) {
                        float arg = S[i][j][r] * CEXP;
                        if (kbase + j * 16 + m16 > qbase + wrow + i * 16 + rq + r)
                            arg = -INFINITY;
#if HAVE_NATIVE_EXP2
                        float e = EXP2F(arg);
#else
                        float e = __expf(arg * 0.6931472f);
#endif
                        S[i][j][r] = e;
                        l_part[i][r] += e;
                    }
        } else {
#pragma unroll
            for (int i = 0; i < 2; i++)
#pragma unroll
                for (int j = 0; j < 4; j++)
#pragma unroll
                    for (int r = 0; r < 4; r++) {
                        float arg = S[i][j][r] * CEXP;
#if HAVE_NATIVE_EXP2
                        float e = EXP2F(arg);
#else
                        float e = __expf(arg * 0.6931472f);
#endif
                        S[i][j][r] = e;
                        l_part[i][r] += e;
                    }
        }

        // ---- write P and Vt to LDS ----
#pragma unroll
        for (int i = 0; i < 2; i++)
#pragma unroll
            for (int j = 0; j < 4; j++)
#pragma unroll
                for (int r = 0; r < 4; r++)
                    Ps[(wrow + i * 16 + rq + r) * 72 + j * 16 + m16] = (__bf16)S[i][j][r];
#pragma unroll
        for (int e = 0; e < 8; e++) {
            bf16x2 pr;
            pr[0] = vc0[e];
            pr[1] = vc1[e];
            *(bf16x2*)(Vt + (dg * 8 + e) * 72 + kp) = pr;
        }
        asm volatile("s_waitcnt lgkmcnt(0)" ::: "memory");
        __builtin_amdgcn_s_barrier();   // barrier2: Ps/Vt visible, Ks[cur] reads retired

        // ---- PV ----
#pragma unroll
        for (int s = 0; s < 2; s++) {
            bf16x8 ap[2], bvv[4];
#pragma unroll
            for (int i = 0; i < 2; i++)
                ap[i] = *(const bf16x8*)(Ps + (wrow + i * 16 + m16) * 72 + s * 32 + kg * 8);
#pragma unroll
            for (int j = 0; j < 4; j++)
                bvv[j] = *(const bf16x8*)(Vt + (j * 16 + m16) * 72 + s * 32 + kg * 8);
            __builtin_amdgcn_s_setprio(1);
#pragma unroll
            for (int i = 0; i < 2; i++)
#pragma unroll
                for (int j = 0; j < 4; j++)
                    Oacc[i][j] = __builtin_amdgcn_mfma_f32_16x16x32_bf16(ap[i], bvv[j], Oacc[i][j], 0, 0, 0);
            __builtin_amdgcn_s_setprio(0);
        }

        if (kt + 1 < nkt) { vc0 = vn0; vc1 = vn1; }
    }

#pragma unroll
    for (int i = 0; i < 2; i++) {
#pragma unroll
        for (int r = 0; r < 4; r++) {
            float l = l_part[i][r];
#pragma unroll
            for (int msk = 1; msk < 16; msk <<= 1) l += __shfl_xor(l, msk, 64);
            const float inv = 1.0f / l;
            const int qrow = qbase + wrow + i * 16 + rq + r;
            __bf16* orow = O + (size_t)(b * Tsz + qrow) * Csz + h * Dsz;
#pragma unroll
            for (int j = 0; j < 4; j++)
                orow[j * 16 + m16] = (__bf16)(Oacc[i][j][r] * inv);
        }
    }
}

// ---------------- launch ----------------------------------------------------

extern "C" void kernel_launch(void* const* d_in, const int* in_sizes, int n_in,
                              void* d_out, int out_size, void* d_ws, size_t ws_size,
                              hipStream_t stream) {
    const float* x     = (const float*)d_in[0];
    const float* Wq    = (const float*)d_in[1];
    const float* Wk    = (const float*)d_in[2];
    const float* Wv    = (const float*)d_in[3];
    const float* Wo    = (const float*)d_in[4];
    const float* bo    = (const float*)d_in[5];
    const float* ln1_g = (const float*)d_in[6];
    const float* ln1_b = (const float*)d_in[7];
    const float* ln2_g = (const float*)d_in[8];
    const float* ln2_b = (const float*)d_in[9];
    const float* W1    = (const float*)d_in[10];
    const float* b1    = (const float*)d_in[11];
    const float* W2    = (const float*)d_in[12];
    const float* b2    = (const float*)d_in[13];
    float* out = (float*)d_out;

    const size_t MB = 1u << 20;
    char* w = (char*)d_ws;
    __bf16* h    = (__bf16*)(w + 0);         // 16 MB (dead after FFN1)
    __bf16* Wqkv = (__bf16*)(w + 16 * MB);   // 6 MB
    __bf16* Wot  = (__bf16*)(w + 22 * MB);   // 2 MB
    __bf16* W1t  = (__bf16*)(w + 24 * MB);   // 8 MB (dead after FFN1)
    __bf16* W2t  = (__bf16*)(w + 32 * MB);   // 8 MB
    __bf16* QKVb = (__bf16*)(w + 40 * MB);   // 48 MB (dead after attn)
    __bf16* AO   = (__bf16*)(w + 88 * MB);   // 16 MB (dead after proj)
    __bf16* ff1  = (__bf16*)(w + 40 * MB);   // 64 MB, overlays QKVb+AO
    float*  p1   = (float*)(w + 0);          // 32 MB, overlays h..W1t during FFN2
    // high-water: 104 MB

    // weight transposes (f32 KxN -> bf16 NxK)
    transpose4_bf16<<<dim3(32, 32, 4), 256, 0, stream>>>(Wq, Wk, Wv, Wo,
                                                         Wqkv, Wqkv + 1024 * 1024, Wqkv + 2048 * 1024, Wot);
    transpose_bf16<<<dim3(4 * Csz / 32, Csz / 32), 256, 0, stream>>>(W1, W1t, Csz, 4 * Csz);
    transpose_bf16<<<dim3(Csz / 32, 4 * Csz / 32), 256, 0, stream>>>(W2, W2t, 4 * Csz, Csz);

    // --- attention branch ---
    layernorm_bf16<<<Msz, 256, 0, stream>>>(x, ln1_g, ln1_b, h);
    gemm256<<<dim3(3 * Csz / 256, Msz / 256), 512, 0, stream>>>(
        h, Wqkv, nullptr, nullptr, QKVb, Msz, 3 * Csz, Csz, Csz, nullptr, nullptr, 0);
    attn_mfma<<<dim3(Bsz * Hsz, Tsz / 128), 256, 0, stream>>>(QKVb, AO);
    // x2 = x + AO @ Wo + bo -> d_out (fp32); N=1024 too narrow for 256^2 grid
    gemm_bf16<<<dim3(Csz / 128, Msz / 128), 256, 0, stream>>>(
        AO, Wot, out, nullptr, nullptr, Msz, Csz, Csz, Csz, bo, x, 0);

    // --- FFN branch ---
    layernorm_bf16<<<Msz, 256, 0, stream>>>(out, ln2_g, ln2_b, h);
    gemm256<<<dim3(4 * Csz / 256, Msz / 256), 512, 0, stream>>>(
        h, W1t, nullptr, nullptr, ff1, Msz, 4 * Csz, Csz, Csz, b1, nullptr, 1);
    // FFN2 split-K=2 on 256^2: z=0 -> out = x2 + ff1[:, :2048]@W2t[:, :2048]^T
    //                          z=1 -> p1  =      ff1[:, 2048:]@W2t[:, 2048:]^T
    gemm256<<<dim3(Csz / 256, Msz / 256, 2), 512, 0, stream>>>(
        ff1, W2t, out, p1, nullptr, Msz, Csz, 2 * Csz, 4 * Csz, nullptr, out, 0);
    add_partial<<<Msz * Csz / 1024, 256, 0, stream>>>(out, p1, b2);
}

// Round 9
// 518.900 us; speedup vs baseline: 1.6591x; 1.6591x over previous
//
#include <hip/hip_runtime.h>
#include <hip/hip_bf16.h>
#include <math.h>

#define Bsz 4
#define Tsz 2048
#define Csz 1024
#define Hsz 16
#define Dsz 64
#define Msz (Bsz * Tsz)   // 8192 rows

typedef __attribute__((ext_vector_type(8))) __bf16 bf16x8;
typedef __attribute__((ext_vector_type(2))) __bf16 bf16x2;
typedef __attribute__((ext_vector_type(4))) float f32x4;

#define GLOBAL_AS __attribute__((address_space(1)))
#define LDS_AS    __attribute__((address_space(3)))

#if __has_builtin(__builtin_amdgcn_exp2f)
#define EXP2F(x) __builtin_amdgcn_exp2f(x)
#define HAVE_NATIVE_EXP2 1
#else
#define HAVE_NATIVE_EXP2 0
#endif

// ---------------- block-wide reductions (256 threads = 4 waves of 64) -------

__device__ __forceinline__ float block_sum256(float v, float* sh) {
#pragma unroll
    for (int o = 32; o > 0; o >>= 1) v += __shfl_down(v, o, 64);
    int lane = threadIdx.x & 63, w = threadIdx.x >> 6;
    __syncthreads();
    if (lane == 0) sh[w] = v;
    __syncthreads();
    return sh[0] + sh[1] + sh[2] + sh[3];
}

// ---------------- LayerNorm -> bf16: one block per row, C=1024 --------------

__global__ __launch_bounds__(256) void layernorm_bf16(const float* __restrict__ x,
                                                      const float* __restrict__ g,
                                                      const float* __restrict__ b,
                                                      __bf16* __restrict__ out) {
    __shared__ float sh[4];
    const int row = blockIdx.x;
    const float* xr = x + (size_t)row * Csz;
    float v[4];
    float s = 0.f, ss = 0.f;
#pragma unroll
    for (int i = 0; i < 4; i++) {
        v[i] = xr[threadIdx.x + i * 256];
        s += v[i];
        ss += v[i] * v[i];
    }
    float tot = block_sum256(s, sh);
    float mean = tot * (1.0f / Csz);
    float tot2 = block_sum256(ss, sh);
    float var = tot2 * (1.0f / Csz) - mean * mean;
    float inv = rsqrtf(var + 1e-5f);
    __bf16* orow = out + (size_t)row * Csz;
#pragma unroll
    for (int i = 0; i < 4; i++) {
        int c = threadIdx.x + i * 256;
        orow[c] = (__bf16)((v[i] - mean) * inv * g[c] + b[c]);
    }
}

// ---------------- all weight transposes in ONE launch ------------------------
// f32 KxN -> bf16 NxK. Linearized tiles: [0,4096) = four 1024^2 (Wq/Wk/Wv/Wo),
// [4096,8192) = W1 (1024x4096), [8192,12288) = W2 (4096x1024). Same per-tile
// math as the original transpose kernels; merging saves two launch gaps.

__global__ __launch_bounds__(256) void transpose_all(const float* __restrict__ Wq,
                                                     const float* __restrict__ Wk,
                                                     const float* __restrict__ Wv,
                                                     const float* __restrict__ Wo,
                                                     const float* __restrict__ W1,
                                                     const float* __restrict__ W2,
                                                     __bf16* __restrict__ Tq,
                                                     __bf16* __restrict__ Tk,
                                                     __bf16* __restrict__ Tv,
                                                     __bf16* __restrict__ To,
                                                     __bf16* __restrict__ T1,
                                                     __bf16* __restrict__ T2) {
    __shared__ float t[32][33];
    const int bid = (int)blockIdx.x;
    const float* W;
    __bf16* Wt;
    int K, N, n0, k0;
    if (bid < 4096) {                 // four 1024x1024, grid was (32,32,4)
        const int z = bid >> 10, tile = bid & 1023;
        W  = (z == 0) ? Wq : (z == 1) ? Wk : (z == 2) ? Wv : Wo;
        Wt = (z == 0) ? Tq : (z == 1) ? Tk : (z == 2) ? Tv : To;
        K = Csz; N = Csz;
        n0 = (tile & 31) * 32; k0 = (tile >> 5) * 32;
    } else if (bid < 8192) {          // W1: K=1024, N=4096, grid was (128,32)
        const int tile = bid - 4096;
        W = W1; Wt = T1; K = Csz; N = 4 * Csz;
        n0 = (tile & 127) * 32; k0 = (tile >> 7) * 32;
    } else {                          // W2: K=4096, N=1024, grid was (32,128)
        const int tile = bid - 8192;
        W = W2; Wt = T2; K = 4 * Csz; N = Csz;
        n0 = (tile & 31) * 32; k0 = (tile >> 5) * 32;
    }
    const int c = threadIdx.x & 31, r8 = threadIdx.x >> 5;
#pragma unroll
    for (int it = 0; it < 4; it++) {
        int r = r8 + it * 8;
        t[r][c] = W[(size_t)(k0 + r) * N + n0 + c];
    }
    __syncthreads();
#pragma unroll
    for (int it = 0; it < 4; it++) {
        int r = r8 + it * 8;  // n-offset
        Wt[(size_t)(n0 + r) * K + k0 + c] = (__bf16)t[c][r];
    }
}

// ---------------- 128x128 bf16 MFMA GEMM (kept for proj: N=1024) ------------

__global__ __launch_bounds__(256) void gemm_bf16(const __bf16* __restrict__ A,
                                                 const __bf16* __restrict__ Bt,
                                                 float* __restrict__ Cf,
                                                 float* __restrict__ Cf2,
                                                 __bf16* __restrict__ Cb,
                                                 int M, int N, int K, int ld,
                                                 const float* __restrict__ bias,
                                                 const float* __restrict__ resid,
                                                 int do_relu) {
    __shared__ __bf16 As[128 * 64];   // 16 KB
    __shared__ __bf16 Bs[128 * 64];   // 16 KB

    const int tid = threadIdx.x;
    const int lane = tid & 63;
    const int w = tid >> 6;

    const int nwg = (int)(gridDim.x * gridDim.y);
    const int did = (int)(blockIdx.y * gridDim.x + blockIdx.x);
    const int work = ((nwg & 7) == 0) ? ((did & 7) * (nwg >> 3) + (did >> 3)) : did;
    const int bx = work % (int)gridDim.x;
    const int by = work / (int)gridDim.x;

    const int rowBase = by * 128;
    const int colBase = bx * 128;
    const int wr = (w & 1) * 64;
    const int wc = (w >> 1) * 64;

    const __bf16* Ak = A + (size_t)blockIdx.z * K;
    const __bf16* Bk = Bt + (size_t)blockIdx.z * K;
    float* Cfu = Cf;
    const float* residu = resid;
    const float* biasu = bias;
    if (blockIdx.z == 1) { Cfu = Cf2; residu = nullptr; biasu = nullptr; }

    const int m16 = lane & 15;
    const int kg = lane >> 4;
    const int swz = m16 & 7;

    const int sr = lane >> 3;     // row within 8-row group
    const int sc = lane & 7;      // LDS chunk slot
    const int gcs = sc ^ sr;      // fetched global chunk (swizzle key row&7)

    f32x4 acc[4][4] = {};

    for (int k0 = 0; k0 < K; k0 += 64) {
        __syncthreads();  // prior-iter LDS reads complete
#pragma unroll
        for (int it = 0; it < 4; it++) {
            int lr = w * 32 + it * 8;
            const __bf16* ga = Ak + (size_t)(rowBase + lr + sr) * ld + k0 + gcs * 8;
            __builtin_amdgcn_global_load_lds((const GLOBAL_AS unsigned int*)ga,
                                             (LDS_AS unsigned int*)(As + lr * 64),
                                             16, 0, 0);
            const __bf16* gb = Bk + (size_t)(colBase + lr + sr) * ld + k0 + gcs * 8;
            __builtin_amdgcn_global_load_lds((const GLOBAL_AS unsigned int*)gb,
                                             (LDS_AS unsigned int*)(Bs + lr * 64),
                                             16, 0, 0);
        }
        __syncthreads();  // drains vmcnt -> tiles visible

#pragma unroll
        for (int s = 0; s < 2; s++) {
            const int slot = ((s * 4 + kg) ^ swz) * 8;
            bf16x8 af[4], bfv[4];
#pragma unroll
            for (int i = 0; i < 4; i++)
                af[i] = *(const bf16x8*)(As + (wr + i * 16 + m16) * 64 + slot);
#pragma unroll
            for (int j = 0; j < 4; j++)
                bfv[j] = *(const bf16x8*)(Bs + (wc + j * 16 + m16) * 64 + slot);
#pragma unroll
            for (int i = 0; i < 4; i++)
#pragma unroll
                for (int j = 0; j < 4; j++)
                    acc[i][j] = __builtin_amdgcn_mfma_f32_16x16x32_bf16(af[i], bfv[j], acc[i][j], 0, 0, 0);
        }
    }

    const int cn = lane & 15;
    const int rq = (lane >> 4) * 4;
    float bj[4];
#pragma unroll
    for (int j = 0; j < 4; j++)
        bj[j] = biasu ? biasu[colBase + wc + j * 16 + cn] : 0.f;

#pragma unroll
    for (int i = 0; i < 4; i++) {
#pragma unroll
        for (int r = 0; r < 4; r++) {
            int m = rowBase + wr + i * 16 + rq + r;
            size_t rowOff = (size_t)m * N;
#pragma unroll
            for (int j = 0; j < 4; j++) {
                int n = colBase + wc + j * 16 + cn;
                float v = acc[i][j][r] + bj[j];
                if (do_relu) v = fmaxf(v, 0.f);
                if (residu) v += residu[rowOff + n];
                if (Cfu) Cfu[rowOff + n] = v;
                if (Cb && blockIdx.z == 0) Cb[rowOff + n] = (__bf16)v;
            }
        }
    }
}

// ---------------- 256x256 8-phase bf16 MFMA GEMM (T3+T4 schedule) -----------
// ROUND-2 SCHEDULE (measured 100.4 us on FFN1) - FINAL for this block shape.
// 512 threads = 8 waves (2 M x 4 N), per-wave 128x64 output, BK=64.
// Half-tiles (A0/A1 = 128 rows, B0/B1 = 128 out-cols), 2 loads/thread each;
// one half-stage per phase, vmcnt(2) only at phases 4/8 (never 0 mid-loop).
// Stage-slot ledger (iter computes t0 in buf0 ph1-4, t0+1 in buf1 ph5-8):
//   ph1:(t0+1)A0  ph2:(t0+1)B1  ph3:(t0+1)A1  ph4:(t0+2)B0 +vmcnt(2)
//   ph5:(t0+2)A0  ph6:(t0+2)B1  ph7:(t0+2)A1  ph8:(t0+3)B0 +vmcnt(2)
// STRUCTURAL CEILING (r7/r8 lesson): an 8-wave block forces 2 waves/SIMD
// co-residency -> hard 256 unified regs/wave (512-reg SIMD file). acc=128
// (AGPR) + 128 VGPR is exactly saturated; ANY extra register demand spills
// to scratch (r7/r8: +64-reg frag prefetch -> WRITE_SIZE 67->251 MB, 2x
// slower; launch_bounds cannot unlock more). Schedule changes at constant
// registers also explored: coarse-batched ledger (r3) = -23%. Next step for
// this GEMM, if any, is a different block shape (4-wave, 512 regs/wave).

#define Tile256 (256 * 64)

#define STAGE_A6(kt, hh) do {                                                      \
    const int bbuf_ = (kt) & 1;                                                    \
    _Pragma("unroll") for (int l_ = 0; l_ < 2; l_++) {                             \
        const int lr_ = (hh) * 128 + w * 16 + l_ * 8;                              \
        const __bf16* ga_ = Ak + (size_t)(rowBase + lr_ + sr) * ld + (kt) * 64 + gcs * 8; \
        __builtin_amdgcn_global_load_lds((const GLOBAL_AS unsigned int*)ga_,       \
            (LDS_AS unsigned int*)(As + bbuf_ * Tile256 + lr_ * 64), 16, 0, 0);    \
    } } while (0)

#define STAGE_B6(kt, hh) do {                                                      \
    const int bbuf_ = (kt) & 1;                                                    \
    _Pragma("unroll") for (int l_ = 0; l_ < 2; l_++) {                             \
        const int lr_ = (hh) * 128 + w * 16 + l_ * 8;                              \
        const __bf16* gb_ = Bk + (size_t)(colBase + lr_ + sr) * ld + (kt) * 64 + gcs * 8; \
        __builtin_amdgcn_global_load_lds((const GLOBAL_AS unsigned int*)gb_,       \
            (LDS_AS unsigned int*)(Bs + bbuf_ * Tile256 + lr_ * 64), 16, 0, 0);    \
    } } while (0)

#define PHASE6(ks, q, bufc, STAGES, VMW) do {                                      \
    bf16x8 af[4];                                                                  \
    _Pragma("unroll") for (int i_ = 0; i_ < 4; i_++)                               \
        af[i_] = *(const bf16x8*)(As + (bufc) * Tile256 +                          \
                  (wm * 128 + ((q) * 4 + i_) * 16 + m16) * 64 +                    \
                  ((((ks) * 4 + kg) ^ swz) * 8));                                  \
    if ((q) == 0) {                                                                \
        _Pragma("unroll") for (int j_ = 0; j_ < 4; j_++)                           \
            bv[j_] = *(const bf16x8*)(Bs + (bufc) * Tile256 +                      \
                      (wn * 64 + j_ * 16 + m16) * 64 +                             \
                      ((((ks) * 4 + kg) ^ swz) * 8));                              \
    }                                                                              \
    STAGES;                                                                        \
    VMW;                                                                           \
    __builtin_amdgcn_s_barrier();                                                  \
    __builtin_amdgcn_s_setprio(1);                                                 \
    _Pragma("unroll") for (int i_ = 0; i_ < 4; i_++)                               \
        _Pragma("unroll") for (int j_ = 0; j_ < 4; j_++)                           \
            acc[(q) * 4 + i_][j_] = __builtin_amdgcn_mfma_f32_16x16x32_bf16(       \
                af[i_], bv[j_], acc[(q) * 4 + i_][j_], 0, 0, 0);                   \
    __builtin_amdgcn_s_setprio(0);                                                 \
    __builtin_amdgcn_s_barrier();                                                  \
} while (0)

__global__ __launch_bounds__(512, 2) void gemm256(const __bf16* __restrict__ A,
                                                  const __bf16* __restrict__ Bt,
                                                  float* __restrict__ Cf,
                                                  float* __restrict__ Cf2,
                                                  __bf16* __restrict__ Cb,
                                                  int M, int N, int K, int ld,
                                                  const float* __restrict__ bias,
                                                  const float* __restrict__ resid,
                                                  int do_relu) {
    __shared__ __bf16 As[2 * Tile256];  // 64 KB
    __shared__ __bf16 Bs[2 * Tile256];  // 64 KB

    const int tid = threadIdx.x;
    const int lane = tid & 63;
    const int w = tid >> 6;        // wave 0..7
    const int wm = w >> 2;         // 0..1 (M half)
    const int wn = w & 3;          // 0..3 (N quarter)

    const int nwg = (int)(gridDim.x * gridDim.y);
    const int did = (int)(blockIdx.y * gridDim.x + blockIdx.x);
    const int work = ((nwg & 7) == 0) ? ((did & 7) * (nwg >> 3) + (did >> 3)) : did;
    const int bx = work % (int)gridDim.x;
    const int by = work / (int)gridDim.x;
    const int rowBase = by * 256;
    const int colBase = bx * 256;

    const __bf16* Ak = A + (size_t)blockIdx.z * K;
    const __bf16* Bk = Bt + (size_t)blockIdx.z * K;
    float* Cfu = Cf;
    const float* residu = resid;
    const float* biasu = bias;
    if (blockIdx.z == 1) { Cfu = Cf2; residu = nullptr; biasu = nullptr; }

    const int m16 = lane & 15;
    const int kg = lane >> 4;
    const int swz = m16 & 7;
    const int sr = lane >> 3;
    const int sc = lane & 7;
    const int gcs = sc ^ sr;

    const int nt = K >> 6;  // K-tiles of 64 -- must be even, >= 4

    f32x4 acc[8][4] = {};
    bf16x8 bv[4];

    // prologue: T0 {A0,B0,A1,B1}, then T1 B0; keep T1B0 in flight
    STAGE_A6(0, 0); STAGE_B6(0, 0); STAGE_A6(0, 1); STAGE_B6(0, 1);
    STAGE_B6(1, 0);
    asm volatile("s_waitcnt vmcnt(2)" ::: "memory");
    __builtin_amdgcn_s_barrier();

    for (int t0 = 0; t0 < nt; t0 += 2) {
        const bool p2 = (t0 + 2 < nt);
        const bool p3 = (t0 + 3 < nt);
        PHASE6(0, 0, 0, STAGE_A6(t0 + 1, 0), );
        PHASE6(0, 1, 0, STAGE_B6(t0 + 1, 1), );
        PHASE6(1, 0, 0, STAGE_A6(t0 + 1, 1), );
        PHASE6(1, 1, 0, if (p2) STAGE_B6(t0 + 2, 0),
               if (p2) asm volatile("s_waitcnt vmcnt(2)" ::: "memory");
               else    asm volatile("s_waitcnt vmcnt(0)" ::: "memory"));
        PHASE6(0, 0, 1, if (p2) STAGE_A6(t0 + 2, 0), );
        PHASE6(0, 1, 1, if (p2) STAGE_B6(t0 + 2, 1), );
        PHASE6(1, 0, 1, if (p2) STAGE_A6(t0 + 2, 1), );
        PHASE6(1, 1, 1, if (p3) STAGE_B6(t0 + 3, 0),
               if (p3) asm volatile("s_waitcnt vmcnt(2)" ::: "memory");
               else    asm volatile("s_waitcnt vmcnt(0)" ::: "memory"));
    }

    // epilogue: C/D layout col=lane&15, row=(lane>>4)*4+reg
    const int cn = lane & 15;
    const int rqe = (lane >> 4) * 4;
    float bj[4];
#pragma unroll
    for (int j = 0; j < 4; j++)
        bj[j] = biasu ? biasu[colBase + wn * 64 + j * 16 + cn] : 0.f;

#pragma unroll
    for (int mi = 0; mi < 8; mi++) {
#pragma unroll
        for (int r = 0; r < 4; r++) {
            const int m = rowBase + wm * 128 + mi * 16 + rqe + r;
            const size_t rowOff = (size_t)m * N;
#pragma unroll
            for (int j = 0; j < 4; j++) {
                const int n = colBase + wn * 64 + j * 16 + cn;
                float v = acc[mi][j][r] + bj[j];
                if (do_relu) v = fmaxf(v, 0.f);
                if (residu) v += residu[rowOff + n];
                if (Cfu) Cfu[rowOff + n] = v;
                if (Cb && blockIdx.z == 0) Cb[rowOff + n] = (__bf16)v;
            }
        }
    }
}

// ---------------- split-K tail: out += p + b2 --------------------------------

__global__ __launch_bounds__(256) void add_partial(float* __restrict__ out,
                                                   const float* __restrict__ p,
                                                   const float* __restrict__ b2) {
    size_t i = ((size_t)blockIdx.x * 256 + threadIdx.x) * 4;
    float4 o = *(float4*)(out + i);
    const float4 a = *(const float4*)(p + i);
    const float4 bb = *(const float4*)(b2 + (i & (Csz - 1)));
    o.x += a.x + bb.x;
    o.y += a.y + bb.y;
    o.z += a.z + bb.z;
    o.w += a.w + bb.w;
    *(float4*)(out + i) = o;
}

// ---------------- MFMA flash attention, static-shift softmax ----------------
// Known-good pipelined version: K-tile kt+1 staged via global_load_lds (zero
// VGPR cost) + V-regs prefetched; raw s_barrier + counted vmcnt(4).

__global__ __launch_bounds__(256, 3) void attn_mfma(const __bf16* __restrict__ QKV,
                                                    __bf16* __restrict__ O) {
    __shared__ __bf16 Ks[2][64 * 64];  // double-buffered, 16 KB
    __shared__ __bf16 Vt[64 * 72];     // Vt[d][key], padded, 9 KB
    __shared__ __bf16 Ps[128 * 72];    // P[q][key], padded, 18 KB -> 43 KB total

    const int tid = threadIdx.x;
    const int lane = tid & 63;
    const int w = tid >> 6;
    const int bh = blockIdx.x;            // 0..63
    const int b = bh >> 4, h = bh & 15;
    const int qt = (int)gridDim.y - 1 - (int)blockIdx.y;  // heavy tiles first
    const int qbase = qt * 128;
    const int ld3C = 3 * Csz;

    const __bf16* Qg = QKV + (size_t)(b * Tsz) * ld3C + h * Dsz;
    const __bf16* Kg = Qg + Csz;
    const __bf16* Vg = Qg + 2 * Csz;

    const int m16 = lane & 15;
    const int kg = lane >> 4;
    const int rq = kg * 4;
    const int wrow = w * 32;
    const int swz = m16 & 7;

    bf16x8 aq[2][2];
#pragma unroll
    for (int i = 0; i < 2; i++)
#pragma unroll
        for (int s = 0; s < 2; s++)
            aq[i][s] = *(const bf16x8*)(Qg + (size_t)(qbase + wrow + i * 16 + m16) * ld3C + (s * 4 + kg) * 8);

    const int sr = lane >> 3;
    const int sc = lane & 7;
    const int gcs = sc ^ sr;

    const int kp = (lane & 31) * 2;
    const int dg = w * 2 + (lane >> 5);

    f32x4 Oacc[2][4];
    float l_part[2][4];
#pragma unroll
    for (int i = 0; i < 2; i++)
#pragma unroll
        for (int j = 0; j < 4; j++) Oacc[i][j] = (f32x4){0.f, 0.f, 0.f, 0.f};
#pragma unroll
    for (int i = 0; i < 2; i++)
#pragma unroll
        for (int r = 0; r < 4; r++) l_part[i][r] = 0.f;

    const float CEXP = 0.18033688f;  // 0.125 * log2(e)
    const int nkt = 2 * qt + 2;

    // ---- prologue: stage kt=0 K-tile + V regs (4 vmem ops in flight) ----
#pragma unroll
    for (int it = 0; it < 2; it++) {
        int lr = w * 16 + it * 8 + sr;
        const __bf16* src = Kg + (size_t)lr * ld3C + gcs * 8;
        __builtin_amdgcn_global_load_lds((const GLOBAL_AS unsigned int*)src,
                                         (LDS_AS unsigned int*)(&Ks[0][(w * 16 + it * 8) * 64]),
                                         16, 0, 0);
    }
    bf16x8 vc0 = *(const bf16x8*)(Vg + (size_t)kp * ld3C + dg * 8);
    bf16x8 vc1 = *(const bf16x8*)(Vg + (size_t)(kp + 1) * ld3C + dg * 8);
    bf16x8 vn0, vn1;

    for (int kt = 0; kt < nkt; kt++) {
        const int cur = kt & 1;
        const int kbase = kt * 64;

        // ---- prefetch kt+1 (K -> Ks[cur^1], V -> regs), then counted wait ----
        if (kt + 1 < nkt) {
            const int nb = kbase + 64;
#pragma unroll
            for (int it = 0; it < 2; it++) {
                int lr = w * 16 + it * 8 + sr;
                const __bf16* src = Kg + (size_t)(nb + lr) * ld3C + gcs * 8;
                __builtin_amdgcn_global_load_lds((const GLOBAL_AS unsigned int*)src,
                                                 (LDS_AS unsigned int*)(&Ks[cur ^ 1][(w * 16 + it * 8) * 64]),
                                                 16, 0, 0);
            }
            vn0 = *(const bf16x8*)(Vg + (size_t)(nb + kp) * ld3C + dg * 8);
            vn1 = *(const bf16x8*)(Vg + (size_t)(nb + kp + 1) * ld3C + dg * 8);
            asm volatile("s_waitcnt vmcnt(4)" ::: "memory");
        } else {
            asm volatile("s_waitcnt vmcnt(0)" ::: "memory");
        }
        __builtin_amdgcn_s_barrier();   // barrier1: Ks[cur] + vc fully landed

        // ---- QK^T ----
        f32x4 S[2][4];
#pragma unroll
        for (int i = 0; i < 2; i++)
#pragma unroll
            for (int j = 0; j < 4; j++) S[i][j] = (f32x4){0.f, 0.f, 0.f, 0.f};
#pragma unroll
        for (int s = 0; s < 2; s++) {
            bf16x8 bk[4];
#pragma unroll
            for (int j = 0; j < 4; j++)
                bk[j] = *(const bf16x8*)(&Ks[cur][(j * 16 + m16) * 64 + (((s * 4 + kg) ^ swz) * 8)]);
            __builtin_amdgcn_s_setprio(1);
#pragma unroll
            for (int i = 0; i < 2; i++)
#pragma unroll
                for (int j = 0; j < 4; j++)
                    S[i][j] = __builtin_amdgcn_mfma_f32_16x16x32_bf16(aq[i][s], bk[j], S[i][j], 0, 0, 0);
            __builtin_amdgcn_s_setprio(0);
        }

        // ---- softmax (uniform branch: mask only on last two tiles) ----
        if (kt >= 2 * qt) {
#pragma unroll
            for (int i = 0; i < 2; i++)
#pragma unroll
                for (int j = 0; j < 4; j++)
#pragma unroll
                    for (int r = 0; r < 4; r++) {
                        float arg = S[i][j][r] * CEXP;
                        if (kbase + j * 16 + m16 > qbase + wrow + i * 16 + rq + r)
                            arg = -INFINITY;
#if HAVE_NATIVE_EXP2
                        float e = EXP2F(arg);
#else
                        float e = __expf(arg * 0.6931472f);
#endif
                        S[i][j][r] = e;
                        l_part[i][r] += e;
                    }
        } else {
#pragma unroll
            for (int i = 0; i < 2; i++)
#pragma unroll
                for (int j = 0; j < 4; j++)
#pragma unroll
                    for (int r = 0; r < 4; r++) {
                        float arg = S[i][j][r] * CEXP;
#if HAVE_NATIVE_EXP2
                        float e = EXP2F(arg);
#else
                        float e = __expf(arg * 0.6931472f);
#endif
                        S[i][j][r] = e;
                        l_part[i][r] += e;
                    }
        }

        // ---- write P and Vt to LDS ----
#pragma unroll
        for (int i = 0; i < 2; i++)
#pragma unroll
            for (int j = 0; j < 4; j++)
#pragma unroll
                for (int r = 0; r < 4; r++)
                    Ps[(wrow + i * 16 + rq + r) * 72 + j * 16 + m16] = (__bf16)S[i][j][r];
#pragma unroll
        for (int e = 0; e < 8; e++) {
            bf16x2 pr;
            pr[0] = vc0[e];
            pr[1] = vc1[e];
            *(bf16x2*)(Vt + (dg * 8 + e) * 72 + kp) = pr;
        }
        asm volatile("s_waitcnt lgkmcnt(0)" ::: "memory");
        __builtin_amdgcn_s_barrier();   // barrier2: Ps/Vt visible, Ks[cur] reads retired

        // ---- PV ----
#pragma unroll
        for (int s = 0; s < 2; s++) {
            bf16x8 ap[2], bvv[4];
#pragma unroll
            for (int i = 0; i < 2; i++)
                ap[i] = *(const bf16x8*)(Ps + (wrow + i * 16 + m16) * 72 + s * 32 + kg * 8);
#pragma unroll
            for (int j = 0; j < 4; j++)
                bvv[j] = *(const bf16x8*)(Vt + (j * 16 + m16) * 72 + s * 32 + kg * 8);
            __builtin_amdgcn_s_setprio(1);
#pragma unroll
            for (int i = 0; i < 2; i++)
#pragma unroll
                for (int j = 0; j < 4; j++)
                    Oacc[i][j] = __builtin_amdgcn_mfma_f32_16x16x32_bf16(ap[i], bvv[j], Oacc[i][j], 0, 0, 0);
            __builtin_amdgcn_s_setprio(0);
        }

        if (kt + 1 < nkt) { vc0 = vn0; vc1 = vn1; }
    }

#pragma unroll
    for (int i = 0; i < 2; i++) {
#pragma unroll
        for (int r = 0; r < 4; r++) {
            float l = l_part[i][r];
#pragma unroll
            for (int msk = 1; msk < 16; msk <<= 1) l += __shfl_xor(l, msk, 64);
            const float inv = 1.0f / l;
            const int qrow = qbase + wrow + i * 16 + rq + r;
            __bf16* orow = O + (size_t)(b * Tsz + qrow) * Csz + h * Dsz;
#pragma unroll
            for (int j = 0; j < 4; j++)
                orow[j * 16 + m16] = (__bf16)(Oacc[i][j][r] * inv);
        }
    }
}

// ---------------- launch ----------------------------------------------------

extern "C" void kernel_launch(void* const* d_in, const int* in_sizes, int n_in,
                              void* d_out, int out_size, void* d_ws, size_t ws_size,
                              hipStream_t stream) {
    const float* x     = (const float*)d_in[0];
    const float* Wq    = (const float*)d_in[1];
    const float* Wk    = (const float*)d_in[2];
    const float* Wv    = (const float*)d_in[3];
    const float* Wo    = (const float*)d_in[4];
    const float* bo    = (const float*)d_in[5];
    const float* ln1_g = (const float*)d_in[6];
    const float* ln1_b = (const float*)d_in[7];
    const float* ln2_g = (const float*)d_in[8];
    const float* ln2_b = (const float*)d_in[9];
    const float* W1    = (const float*)d_in[10];
    const float* b1    = (const float*)d_in[11];
    const float* W2    = (const float*)d_in[12];
    const float* b2    = (const float*)d_in[13];
    float* out = (float*)d_out;

    const size_t MB = 1u << 20;
    char* w = (char*)d_ws;
    __bf16* h    = (__bf16*)(w + 0);         // 16 MB (dead after FFN1)
    __bf16* Wqkv = (__bf16*)(w + 16 * MB);   // 6 MB
    __bf16* Wot  = (__bf16*)(w + 22 * MB);   // 2 MB
    __bf16* W1t  = (__bf16*)(w + 24 * MB);   // 8 MB (dead after FFN1)
    __bf16* W2t  = (__bf16*)(w + 32 * MB);   // 8 MB
    __bf16* QKVb = (__bf16*)(w + 40 * MB);   // 48 MB (dead after attn)
    __bf16* AO   = (__bf16*)(w + 88 * MB);   // 16 MB (dead after proj)
    __bf16* ff1  = (__bf16*)(w + 40 * MB);   // 64 MB, overlays QKVb+AO
    float*  p1   = (float*)(w + 0);          // 32 MB, overlays h..W1t during FFN2
    // high-water: 104 MB

    // all weight transposes (f32 KxN -> bf16 NxK) in one launch
    transpose_all<<<12288, 256, 0, stream>>>(Wq, Wk, Wv, Wo, W1, W2,
                                             Wqkv, Wqkv + 1024 * 1024, Wqkv + 2048 * 1024, Wot,
                                             W1t, W2t);

    // --- attention branch ---
    layernorm_bf16<<<Msz, 256, 0, stream>>>(x, ln1_g, ln1_b, h);
    gemm256<<<dim3(3 * Csz / 256, Msz / 256), 512, 0, stream>>>(
        h, Wqkv, nullptr, nullptr, QKVb, Msz, 3 * Csz, Csz, Csz, nullptr, nullptr, 0);
    attn_mfma<<<dim3(Bsz * Hsz, Tsz / 128), 256, 0, stream>>>(QKVb, AO);
    // x2 = x + AO @ Wo + bo -> d_out (fp32); N=1024 too narrow for 256^2 grid
    gemm_bf16<<<dim3(Csz / 128, Msz / 128), 256, 0, stream>>>(
        AO, Wot, out, nullptr, nullptr, Msz, Csz, Csz, Csz, bo, x, 0);

    // --- FFN branch ---
    layernorm_bf16<<<Msz, 256, 0, stream>>>(out, ln2_g, ln2_b, h);
    gemm256<<<dim3(4 * Csz / 256, Msz / 256), 512, 0, stream>>>(
        h, W1t, nullptr, nullptr, ff1, Msz, 4 * Csz, Csz, Csz, b1, nullptr, 1);
    // FFN2 split-K=2 on 256^2: z=0 -> out = x2 + ff1[:, :2048]@W2t[:, :2048]^T
    //                          z=1 -> p1  =      ff1[:, 2048:]@W2t[:, 2048:]^T
    gemm256<<<dim3(Csz / 256, Msz / 256, 2), 512, 0, stream>>>(
        ff1, W2t, out, p1, nullptr, Msz, Csz, 2 * Csz, 4 * Csz, nullptr, out, 0);
    add_partial<<<Msz * Csz / 1024, 256, 0, stream>>>(out, p1, b2);
}

// Round 10
// 506.753 us; speedup vs baseline: 1.6989x; 1.0240x over previous
//
#include <hip/hip_runtime.h>
#include <hip/hip_bf16.h>
#include <math.h>

#define Bsz 4
#define Tsz 2048
#define Csz 1024
#define Hsz 16
#define Dsz 64
#define Msz (Bsz * Tsz)   // 8192 rows

typedef __attribute__((ext_vector_type(8))) __bf16 bf16x8;
typedef __attribute__((ext_vector_type(2))) __bf16 bf16x2;
typedef __attribute__((ext_vector_type(4))) float f32x4;

#define GLOBAL_AS __attribute__((address_space(1)))
#define LDS_AS    __attribute__((address_space(3)))

#if __has_builtin(__builtin_amdgcn_exp2f)
#define EXP2F(x) __builtin_amdgcn_exp2f(x)
#define HAVE_NATIVE_EXP2 1
#else
#define HAVE_NATIVE_EXP2 0
#endif

// ---------------- block-wide reductions (256 threads = 4 waves of 64) -------

__device__ __forceinline__ float block_sum256(float v, float* sh) {
#pragma unroll
    for (int o = 32; o > 0; o >>= 1) v += __shfl_down(v, o, 64);
    int lane = threadIdx.x & 63, w = threadIdx.x >> 6;
    __syncthreads();
    if (lane == 0) sh[w] = v;
    __syncthreads();
    return sh[0] + sh[1] + sh[2] + sh[3];
}

// ---------------- LayerNorm -> bf16: one block per row, C=1024 --------------

__global__ __launch_bounds__(256) void layernorm_bf16(const float* __restrict__ x,
                                                      const float* __restrict__ g,
                                                      const float* __restrict__ b,
                                                      __bf16* __restrict__ out) {
    __shared__ float sh[4];
    const int row = blockIdx.x;
    const float* xr = x + (size_t)row * Csz;
    float v[4];
    float s = 0.f, ss = 0.f;
#pragma unroll
    for (int i = 0; i < 4; i++) {
        v[i] = xr[threadIdx.x + i * 256];
        s += v[i];
        ss += v[i] * v[i];
    }
    float tot = block_sum256(s, sh);
    float mean = tot * (1.0f / Csz);
    float tot2 = block_sum256(ss, sh);
    float var = tot2 * (1.0f / Csz) - mean * mean;
    float inv = rsqrtf(var + 1e-5f);
    __bf16* orow = out + (size_t)row * Csz;
#pragma unroll
    for (int i = 0; i < 4; i++) {
        int c = threadIdx.x + i * 256;
        orow[c] = (__bf16)((v[i] - mean) * inv * g[c] + b[c]);
    }
}

// ---------------- all weight transposes in ONE launch ------------------------
// f32 KxN -> bf16 NxK. Linearized tiles: [0,4096) = four 1024^2 (Wq/Wk/Wv/Wo),
// [4096,8192) = W1 (1024x4096), [8192,12288) = W2 (4096x1024).

__global__ __launch_bounds__(256) void transpose_all(const float* __restrict__ Wq,
                                                     const float* __restrict__ Wk,
                                                     const float* __restrict__ Wv,
                                                     const float* __restrict__ Wo,
                                                     const float* __restrict__ W1,
                                                     const float* __restrict__ W2,
                                                     __bf16* __restrict__ Tq,
                                                     __bf16* __restrict__ Tk,
                                                     __bf16* __restrict__ Tv,
                                                     __bf16* __restrict__ To,
                                                     __bf16* __restrict__ T1,
                                                     __bf16* __restrict__ T2) {
    __shared__ float t[32][33];
    const int bid = (int)blockIdx.x;
    const float* W;
    __bf16* Wt;
    int K, N, n0, k0;
    if (bid < 4096) {                 // four 1024x1024
        const int z = bid >> 10, tile = bid & 1023;
        W  = (z == 0) ? Wq : (z == 1) ? Wk : (z == 2) ? Wv : Wo;
        Wt = (z == 0) ? Tq : (z == 1) ? Tk : (z == 2) ? Tv : To;
        K = Csz; N = Csz;
        n0 = (tile & 31) * 32; k0 = (tile >> 5) * 32;
    } else if (bid < 8192) {          // W1: K=1024, N=4096
        const int tile = bid - 4096;
        W = W1; Wt = T1; K = Csz; N = 4 * Csz;
        n0 = (tile & 127) * 32; k0 = (tile >> 7) * 32;
    } else {                          // W2: K=4096, N=1024
        const int tile = bid - 8192;
        W = W2; Wt = T2; K = 4 * Csz; N = Csz;
        n0 = (tile & 31) * 32; k0 = (tile >> 5) * 32;
    }
    const int c = threadIdx.x & 31, r8 = threadIdx.x >> 5;
#pragma unroll
    for (int it = 0; it < 4; it++) {
        int r = r8 + it * 8;
        t[r][c] = W[(size_t)(k0 + r) * N + n0 + c];
    }
    __syncthreads();
#pragma unroll
    for (int it = 0; it < 4; it++) {
        int r = r8 + it * 8;  // n-offset
        Wt[(size_t)(n0 + r) * K + k0 + c] = (__bf16)t[c][r];
    }
}

// ---------------- 128x128 bf16 MFMA GEMM (proj + QKV) ------------------------
// 4 blocks/CU -> no grid-tail waste at non-multiple-of-256 block counts.
// QKV (384x 256^2-blocks = 1.5 CU-waves on gemm256) runs HERE instead:
// 1536 blocks = 6 exact CU-waves at ~650 TF -> ~79 us vs gemm256's 103.

__global__ __launch_bounds__(256) void gemm_bf16(const __bf16* __restrict__ A,
                                                 const __bf16* __restrict__ Bt,
                                                 float* __restrict__ Cf,
                                                 float* __restrict__ Cf2,
                                                 __bf16* __restrict__ Cb,
                                                 int M, int N, int K, int ld,
                                                 const float* __restrict__ bias,
                                                 const float* __restrict__ resid,
                                                 int do_relu) {
    __shared__ __bf16 As[128 * 64];   // 16 KB
    __shared__ __bf16 Bs[128 * 64];   // 16 KB

    const int tid = threadIdx.x;
    const int lane = tid & 63;
    const int w = tid >> 6;

    const int nwg = (int)(gridDim.x * gridDim.y);
    const int did = (int)(blockIdx.y * gridDim.x + blockIdx.x);
    const int work = ((nwg & 7) == 0) ? ((did & 7) * (nwg >> 3) + (did >> 3)) : did;
    const int bx = work % (int)gridDim.x;
    const int by = work / (int)gridDim.x;

    const int rowBase = by * 128;
    const int colBase = bx * 128;
    const int wr = (w & 1) * 64;
    const int wc = (w >> 1) * 64;

    const __bf16* Ak = A + (size_t)blockIdx.z * K;
    const __bf16* Bk = Bt + (size_t)blockIdx.z * K;
    float* Cfu = Cf;
    const float* residu = resid;
    const float* biasu = bias;
    if (blockIdx.z == 1) { Cfu = Cf2; residu = nullptr; biasu = nullptr; }

    const int m16 = lane & 15;
    const int kg = lane >> 4;
    const int swz = m16 & 7;

    const int sr = lane >> 3;     // row within 8-row group
    const int sc = lane & 7;      // LDS chunk slot
    const int gcs = sc ^ sr;      // fetched global chunk (swizzle key row&7)

    f32x4 acc[4][4] = {};

    for (int k0 = 0; k0 < K; k0 += 64) {
        __syncthreads();  // prior-iter LDS reads complete
#pragma unroll
        for (int it = 0; it < 4; it++) {
            int lr = w * 32 + it * 8;
            const __bf16* ga = Ak + (size_t)(rowBase + lr + sr) * ld + k0 + gcs * 8;
            __builtin_amdgcn_global_load_lds((const GLOBAL_AS unsigned int*)ga,
                                             (LDS_AS unsigned int*)(As + lr * 64),
                                             16, 0, 0);
            const __bf16* gb = Bk + (size_t)(colBase + lr + sr) * ld + k0 + gcs * 8;
            __builtin_amdgcn_global_load_lds((const GLOBAL_AS unsigned int*)gb,
                                             (LDS_AS unsigned int*)(Bs + lr * 64),
                                             16, 0, 0);
        }
        __syncthreads();  // drains vmcnt -> tiles visible

#pragma unroll
        for (int s = 0; s < 2; s++) {
            const int slot = ((s * 4 + kg) ^ swz) * 8;
            bf16x8 af[4], bfv[4];
#pragma unroll
            for (int i = 0; i < 4; i++)
                af[i] = *(const bf16x8*)(As + (wr + i * 16 + m16) * 64 + slot);
#pragma unroll
            for (int j = 0; j < 4; j++)
                bfv[j] = *(const bf16x8*)(Bs + (wc + j * 16 + m16) * 64 + slot);
#pragma unroll
            for (int i = 0; i < 4; i++)
#pragma unroll
                for (int j = 0; j < 4; j++)
                    acc[i][j] = __builtin_amdgcn_mfma_f32_16x16x32_bf16(af[i], bfv[j], acc[i][j], 0, 0, 0);
        }
    }

    const int cn = lane & 15;
    const int rq = (lane >> 4) * 4;
    float bj[4];
#pragma unroll
    for (int j = 0; j < 4; j++)
        bj[j] = biasu ? biasu[colBase + wc + j * 16 + cn] : 0.f;

#pragma unroll
    for (int i = 0; i < 4; i++) {
#pragma unroll
        for (int r = 0; r < 4; r++) {
            int m = rowBase + wr + i * 16 + rq + r;
            size_t rowOff = (size_t)m * N;
#pragma unroll
            for (int j = 0; j < 4; j++) {
                int n = colBase + wc + j * 16 + cn;
                float v = acc[i][j][r] + bj[j];
                if (do_relu) v = fmaxf(v, 0.f);
                if (residu) v += residu[rowOff + n];
                if (Cfu) Cfu[rowOff + n] = v;
                if (Cb && blockIdx.z == 0) Cb[rowOff + n] = (__bf16)v;
            }
        }
    }
}

// ---------------- 256x256 8-phase bf16 MFMA GEMM (T3+T4 schedule) -----------
// ROUND-2 SCHEDULE (measured 100.4 us on FFN1) - FINAL for this block shape.
// STRUCTURAL CEILING (r7/r8): 8-wave block -> 2 waves/SIMD -> hard 256
// unified regs/wave; acc(128 AGPR)+128 VGPR saturated; any extra register
// demand spills (frag-prefetch attempts: WRITE_SIZE 67->251 MB, 2x slower).
// NEW (r10): do_atomic epilogue - both split-K slices atomicAdd into Cf
// (dest pre-initialized with the residual by the preceding kernel), removing
// the separate add_partial pass and the p1 buffer.

#define Tile256 (256 * 64)

#define STAGE_A6(kt, hh) do {                                                      \
    const int bbuf_ = (kt) & 1;                                                    \
    _Pragma("unroll") for (int l_ = 0; l_ < 2; l_++) {                             \
        const int lr_ = (hh) * 128 + w * 16 + l_ * 8;                              \
        const __bf16* ga_ = Ak + (size_t)(rowBase + lr_ + sr) * ld + (kt) * 64 + gcs * 8; \
        __builtin_amdgcn_global_load_lds((const GLOBAL_AS unsigned int*)ga_,       \
            (LDS_AS unsigned int*)(As + bbuf_ * Tile256 + lr_ * 64), 16, 0, 0);    \
    } } while (0)

#define STAGE_B6(kt, hh) do {                                                      \
    const int bbuf_ = (kt) & 1;                                                    \
    _Pragma("unroll") for (int l_ = 0; l_ < 2; l_++) {                             \
        const int lr_ = (hh) * 128 + w * 16 + l_ * 8;                              \
        const __bf16* gb_ = Bk + (size_t)(colBase + lr_ + sr) * ld + (kt) * 64 + gcs * 8; \
        __builtin_amdgcn_global_load_lds((const GLOBAL_AS unsigned int*)gb_,       \
            (LDS_AS unsigned int*)(Bs + bbuf_ * Tile256 + lr_ * 64), 16, 0, 0);    \
    } } while (0)

#define PHASE6(ks, q, bufc, STAGES, VMW) do {                                      \
    bf16x8 af[4];                                                                  \
    _Pragma("unroll") for (int i_ = 0; i_ < 4; i_++)                               \
        af[i_] = *(const bf16x8*)(As + (bufc) * Tile256 +                          \
                  (wm * 128 + ((q) * 4 + i_) * 16 + m16) * 64 +                    \
                  ((((ks) * 4 + kg) ^ swz) * 8));                                  \
    if ((q) == 0) {                                                                \
        _Pragma("unroll") for (int j_ = 0; j_ < 4; j_++)                           \
            bv[j_] = *(const bf16x8*)(Bs + (bufc) * Tile256 +                      \
                      (wn * 64 + j_ * 16 + m16) * 64 +                             \
                      ((((ks) * 4 + kg) ^ swz) * 8));                              \
    }                                                                              \
    STAGES;                                                                        \
    VMW;                                                                           \
    __builtin_amdgcn_s_barrier();                                                  \
    __builtin_amdgcn_s_setprio(1);                                                 \
    _Pragma("unroll") for (int i_ = 0; i_ < 4; i_++)                               \
        _Pragma("unroll") for (int j_ = 0; j_ < 4; j_++)                           \
            acc[(q) * 4 + i_][j_] = __builtin_amdgcn_mfma_f32_16x16x32_bf16(       \
                af[i_], bv[j_], acc[(q) * 4 + i_][j_], 0, 0, 0);                   \
    __builtin_amdgcn_s_setprio(0);                                                 \
    __builtin_amdgcn_s_barrier();                                                  \
} while (0)

__global__ __launch_bounds__(512, 2) void gemm256(const __bf16* __restrict__ A,
                                                  const __bf16* __restrict__ Bt,
                                                  float* __restrict__ Cf,
                                                  float* __restrict__ Cf2,
                                                  __bf16* __restrict__ Cb,
                                                  int M, int N, int K, int ld,
                                                  const float* __restrict__ bias,
                                                  const float* __restrict__ resid,
                                                  int do_relu, int do_atomic) {
    __shared__ __bf16 As[2 * Tile256];  // 64 KB
    __shared__ __bf16 Bs[2 * Tile256];  // 64 KB

    const int tid = threadIdx.x;
    const int lane = tid & 63;
    const int w = tid >> 6;        // wave 0..7
    const int wm = w >> 2;         // 0..1 (M half)
    const int wn = w & 3;          // 0..3 (N quarter)

    const int nwg = (int)(gridDim.x * gridDim.y);
    const int did = (int)(blockIdx.y * gridDim.x + blockIdx.x);
    const int work = ((nwg & 7) == 0) ? ((did & 7) * (nwg >> 3) + (did >> 3)) : did;
    const int bx = work % (int)gridDim.x;
    const int by = work / (int)gridDim.x;
    const int rowBase = by * 256;
    const int colBase = bx * 256;

    const __bf16* Ak = A + (size_t)blockIdx.z * K;
    const __bf16* Bk = Bt + (size_t)blockIdx.z * K;
    float* Cfu = Cf;
    const float* residu = resid;
    const float* biasu = bias;
    if (blockIdx.z == 1) { Cfu = Cf2; residu = nullptr; biasu = nullptr; }

    const int m16 = lane & 15;
    const int kg = lane >> 4;
    const int swz = m16 & 7;
    const int sr = lane >> 3;
    const int sc = lane & 7;
    const int gcs = sc ^ sr;

    const int nt = K >> 6;  // K-tiles of 64 -- must be even, >= 4

    f32x4 acc[8][4] = {};
    bf16x8 bv[4];

    // prologue: T0 {A0,B0,A1,B1}, then T1 B0; keep T1B0 in flight
    STAGE_A6(0, 0); STAGE_B6(0, 0); STAGE_A6(0, 1); STAGE_B6(0, 1);
    STAGE_B6(1, 0);
    asm volatile("s_waitcnt vmcnt(2)" ::: "memory");
    __builtin_amdgcn_s_barrier();

    for (int t0 = 0; t0 < nt; t0 += 2) {
        const bool p2 = (t0 + 2 < nt);
        const bool p3 = (t0 + 3 < nt);
        PHASE6(0, 0, 0, STAGE_A6(t0 + 1, 0), );
        PHASE6(0, 1, 0, STAGE_B6(t0 + 1, 1), );
        PHASE6(1, 0, 0, STAGE_A6(t0 + 1, 1), );
        PHASE6(1, 1, 0, if (p2) STAGE_B6(t0 + 2, 0),
               if (p2) asm volatile("s_waitcnt vmcnt(2)" ::: "memory");
               else    asm volatile("s_waitcnt vmcnt(0)" ::: "memory"));
        PHASE6(0, 0, 1, if (p2) STAGE_A6(t0 + 2, 0), );
        PHASE6(0, 1, 1, if (p2) STAGE_B6(t0 + 2, 1), );
        PHASE6(1, 0, 1, if (p2) STAGE_A6(t0 + 2, 1), );
        PHASE6(1, 1, 1, if (p3) STAGE_B6(t0 + 3, 0),
               if (p3) asm volatile("s_waitcnt vmcnt(2)" ::: "memory");
               else    asm volatile("s_waitcnt vmcnt(0)" ::: "memory"));
    }

    // epilogue: C/D layout col=lane&15, row=(lane>>4)*4+reg
    const int cn = lane & 15;
    const int rqe = (lane >> 4) * 4;
    float bj[4];
#pragma unroll
    for (int j = 0; j < 4; j++)
        bj[j] = biasu ? biasu[colBase + wn * 64 + j * 16 + cn] : 0.f;

#pragma unroll
    for (int mi = 0; mi < 8; mi++) {
#pragma unroll
        for (int r = 0; r < 4; r++) {
            const int m = rowBase + wm * 128 + mi * 16 + rqe + r;
            const size_t rowOff = (size_t)m * N;
#pragma unroll
            for (int j = 0; j < 4; j++) {
                const int n = colBase + wn * 64 + j * 16 + cn;
                float v = acc[mi][j][r] + bj[j];
                if (do_relu) v = fmaxf(v, 0.f);
                if (do_atomic) {
                    atomicAdd(&Cfu[rowOff + n], v);
                } else {
                    if (residu) v += residu[rowOff + n];
                    if (Cfu) Cfu[rowOff + n] = v;
                    if (Cb && blockIdx.z == 0) Cb[rowOff + n] = (__bf16)v;
                }
            }
        }
    }
}

// ---------------- MFMA flash attention, static-shift softmax ----------------
// Known-good pipelined version: K-tile kt+1 staged via global_load_lds (zero
// VGPR cost) + V-regs prefetched; raw s_barrier + counted vmcnt(4).

__global__ __launch_bounds__(256, 3) void attn_mfma(const __bf16* __restrict__ QKV,
                                                    __bf16* __restrict__ O) {
    __shared__ __bf16 Ks[2][64 * 64];  // double-buffered, 16 KB
    __shared__ __bf16 Vt[64 * 72];     // Vt[d][key], padded, 9 KB
    __shared__ __bf16 Ps[128 * 72];    // P[q][key], padded, 18 KB -> 43 KB total

    const int tid = threadIdx.x;
    const int lane = tid & 63;
    const int w = tid >> 6;
    const int bh = blockIdx.x;            // 0..63
    const int b = bh >> 4, h = bh & 15;
    const int qt = (int)gridDim.y - 1 - (int)blockIdx.y;  // heavy tiles first
    const int qbase = qt * 128;
    const int ld3C = 3 * Csz;

    const __bf16* Qg = QKV + (size_t)(b * Tsz) * ld3C + h * Dsz;
    const __bf16* Kg = Qg + Csz;
    const __bf16* Vg = Qg + 2 * Csz;

    const int m16 = lane & 15;
    const int kg = lane >> 4;
    const int rq = kg * 4;
    const int wrow = w * 32;
    const int swz = m16 & 7;

    bf16x8 aq[2][2];
#pragma unroll
    for (int i = 0; i < 2; i++)
#pragma unroll
        for (int s = 0; s < 2; s++)
            aq[i][s] = *(const bf16x8*)(Qg + (size_t)(qbase + wrow + i * 16 + m16) * ld3C + (s * 4 + kg) * 8);

    const int sr = lane >> 3;
    const int sc = lane & 7;
    const int gcs = sc ^ sr;

    const int kp = (lane & 31) * 2;
    const int dg = w * 2 + (lane >> 5);

    f32x4 Oacc[2][4];
    float l_part[2][4];
#pragma unroll
    for (int i = 0; i < 2; i++)
#pragma unroll
        for (int j = 0; j < 4; j++) Oacc[i][j] = (f32x4){0.f, 0.f, 0.f, 0.f};
#pragma unroll
    for (int i = 0; i < 2; i++)
#pragma unroll
        for (int r = 0; r < 4; r++) l_part[i][r] = 0.f;

    const float CEXP = 0.18033688f;  // 0.125 * log2(e)
    const int nkt = 2 * qt + 2;

    // ---- prologue: stage kt=0 K-tile + V regs (4 vmem ops in flight) ----
#pragma unroll
    for (int it = 0; it < 2; it++) {
        int lr = w * 16 + it * 8 + sr;
        const __bf16* src = Kg + (size_t)lr * ld3C + gcs * 8;
        __builtin_amdgcn_global_load_lds((const GLOBAL_AS unsigned int*)src,
                                         (LDS_AS unsigned int*)(&Ks[0][(w * 16 + it * 8) * 64]),
                                         16, 0, 0);
    }
    bf16x8 vc0 = *(const bf16x8*)(Vg + (size_t)kp * ld3C + dg * 8);
    bf16x8 vc1 = *(const bf16x8*)(Vg + (size_t)(kp + 1) * ld3C + dg * 8);
    bf16x8 vn0, vn1;

    for (int kt = 0; kt < nkt; kt++) {
        const int cur = kt & 1;
        const int kbase = kt * 64;

        // ---- prefetch kt+1 (K -> Ks[cur^1], V -> regs), then counted wait ----
        if (kt + 1 < nkt) {
            const int nb = kbase + 64;
#pragma unroll
            for (int it = 0; it < 2; it++) {
                int lr = w * 16 + it * 8 + sr;
                const __bf16* src = Kg + (size_t)(nb + lr) * ld3C + gcs * 8;
                __builtin_amdgcn_global_load_lds((const GLOBAL_AS unsigned int*)src,
                                                 (LDS_AS unsigned int*)(&Ks[cur ^ 1][(w * 16 + it * 8) * 64]),
                                                 16, 0, 0);
            }
            vn0 = *(const bf16x8*)(Vg + (size_t)(nb + kp) * ld3C + dg * 8);
            vn1 = *(const bf16x8*)(Vg + (size_t)(nb + kp + 1) * ld3C + dg * 8);
            asm volatile("s_waitcnt vmcnt(4)" ::: "memory");
        } else {
            asm volatile("s_waitcnt vmcnt(0)" ::: "memory");
        }
        __builtin_amdgcn_s_barrier();   // barrier1: Ks[cur] + vc fully landed

        // ---- QK^T ----
        f32x4 S[2][4];
#pragma unroll
        for (int i = 0; i < 2; i++)
#pragma unroll
            for (int j = 0; j < 4; j++) S[i][j] = (f32x4){0.f, 0.f, 0.f, 0.f};
#pragma unroll
        for (int s = 0; s < 2; s++) {
            bf16x8 bk[4];
#pragma unroll
            for (int j = 0; j < 4; j++)
                bk[j] = *(const bf16x8*)(&Ks[cur][(j * 16 + m16) * 64 + (((s * 4 + kg) ^ swz) * 8)]);
            __builtin_amdgcn_s_setprio(1);
#pragma unroll
            for (int i = 0; i < 2; i++)
#pragma unroll
                for (int j = 0; j < 4; j++)
                    S[i][j] = __builtin_amdgcn_mfma_f32_16x16x32_bf16(aq[i][s], bk[j], S[i][j], 0, 0, 0);
            __builtin_amdgcn_s_setprio(0);
        }

        // ---- softmax (uniform branch: mask only on last two tiles) ----
        if (kt >= 2 * qt) {
#pragma unroll
            for (int i = 0; i < 2; i++)
#pragma unroll
                for (int j = 0; j < 4; j++)
#pragma unroll
                    for (int r = 0; r < 4; r++) {
                        float arg = S[i][j][r] * CEXP;
                        if (kbase + j * 16 + m16 > qbase + wrow + i * 16 + rq + r)
                            arg = -INFINITY;
#if HAVE_NATIVE_EXP2
                        float e = EXP2F(arg);
#else
                        float e = __expf(arg * 0.6931472f);
#endif
                        S[i][j][r] = e;
                        l_part[i][r] += e;
                    }
        } else {
#pragma unroll
            for (int i = 0; i < 2; i++)
#pragma unroll
                for (int j = 0; j < 4; j++)
#pragma unroll
                    for (int r = 0; r < 4; r++) {
                        float arg = S[i][j][r] * CEXP;
#if HAVE_NATIVE_EXP2
                        float e = EXP2F(arg);
#else
                        float e = __expf(arg * 0.6931472f);
#endif
                        S[i][j][r] = e;
                        l_part[i][r] += e;
                    }
        }

        // ---- write P and Vt to LDS ----
#pragma unroll
        for (int i = 0; i < 2; i++)
#pragma unroll
            for (int j = 0; j < 4; j++)
#pragma unroll
                for (int r = 0; r < 4; r++)
                    Ps[(wrow + i * 16 + rq + r) * 72 + j * 16 + m16] = (__bf16)S[i][j][r];
#pragma unroll
        for (int e = 0; e < 8; e++) {
            bf16x2 pr;
            pr[0] = vc0[e];
            pr[1] = vc1[e];
            *(bf16x2*)(Vt + (dg * 8 + e) * 72 + kp) = pr;
        }
        asm volatile("s_waitcnt lgkmcnt(0)" ::: "memory");
        __builtin_amdgcn_s_barrier();   // barrier2: Ps/Vt visible, Ks[cur] reads retired

        // ---- PV ----
#pragma unroll
        for (int s = 0; s < 2; s++) {
            bf16x8 ap[2], bvv[4];
#pragma unroll
            for (int i = 0; i < 2; i++)
                ap[i] = *(const bf16x8*)(Ps + (wrow + i * 16 + m16) * 72 + s * 32 + kg * 8);
#pragma unroll
            for (int j = 0; j < 4; j++)
                bvv[j] = *(const bf16x8*)(Vt + (j * 16 + m16) * 72 + s * 32 + kg * 8);
            __builtin_amdgcn_s_setprio(1);
#pragma unroll
            for (int i = 0; i < 2; i++)
#pragma unroll
                for (int j = 0; j < 4; j++)
                    Oacc[i][j] = __builtin_amdgcn_mfma_f32_16x16x32_bf16(ap[i], bvv[j], Oacc[i][j], 0, 0, 0);
            __builtin_amdgcn_s_setprio(0);
        }

        if (kt + 1 < nkt) { vc0 = vn0; vc1 = vn1; }
    }

#pragma unroll
    for (int i = 0; i < 2; i++) {
#pragma unroll
        for (int r = 0; r < 4; r++) {
            float l = l_part[i][r];
#pragma unroll
            for (int msk = 1; msk < 16; msk <<= 1) l += __shfl_xor(l, msk, 64);
            const float inv = 1.0f / l;
            const int qrow = qbase + wrow + i * 16 + rq + r;
            __bf16* orow = O + (size_t)(b * Tsz + qrow) * Csz + h * Dsz;
#pragma unroll
            for (int j = 0; j < 4; j++)
                orow[j * 16 + m16] = (__bf16)(Oacc[i][j][r] * inv);
        }
    }
}

// ---------------- launch ----------------------------------------------------

extern "C" void kernel_launch(void* const* d_in, const int* in_sizes, int n_in,
                              void* d_out, int out_size, void* d_ws, size_t ws_size,
                              hipStream_t stream) {
    const float* x     = (const float*)d_in[0];
    const float* Wq    = (const float*)d_in[1];
    const float* Wk    = (const float*)d_in[2];
    const float* Wv    = (const float*)d_in[3];
    const float* Wo    = (const float*)d_in[4];
    const float* bo    = (const float*)d_in[5];
    const float* ln1_g = (const float*)d_in[6];
    const float* ln1_b = (const float*)d_in[7];
    const float* ln2_g = (const float*)d_in[8];
    const float* ln2_b = (const float*)d_in[9];
    const float* W1    = (const float*)d_in[10];
    const float* b1    = (const float*)d_in[11];
    const float* W2    = (const float*)d_in[12];
    const float* b2    = (const float*)d_in[13];
    float* out = (float*)d_out;

    const size_t MB = 1u << 20;
    char* w = (char*)d_ws;
    __bf16* h    = (__bf16*)(w + 0);         // 16 MB (dead after FFN1)
    __bf16* Wqkv = (__bf16*)(w + 16 * MB);   // 6 MB
    __bf16* Wot  = (__bf16*)(w + 22 * MB);   // 2 MB
    __bf16* W1t  = (__bf16*)(w + 24 * MB);   // 8 MB (dead after FFN1)
    __bf16* W2t  = (__bf16*)(w + 32 * MB);   // 8 MB
    __bf16* QKVb = (__bf16*)(w + 40 * MB);   // 48 MB (dead after attn)
    __bf16* AO   = (__bf16*)(w + 88 * MB);   // 16 MB (dead after proj)
    __bf16* ff1  = (__bf16*)(w + 40 * MB);   // 64 MB, overlays QKVb+AO
    // high-water: 104 MB (p1 partial buffer no longer needed)

    // all weight transposes (f32 KxN -> bf16 NxK) in one launch
    transpose_all<<<12288, 256, 0, stream>>>(Wq, Wk, Wv, Wo, W1, W2,
                                             Wqkv, Wqkv + 1024 * 1024, Wqkv + 2048 * 1024, Wot,
                                             W1t, W2t);

    // --- attention branch ---
    layernorm_bf16<<<Msz, 256, 0, stream>>>(x, ln1_g, ln1_b, h);
    // QKV on the 128^2 kernel: 1536 blocks = 6 exact CU-waves (gemm256's 384
    // 1-block/CU grid = 1.5 waves -> half-idle tail round)
    gemm_bf16<<<dim3(3 * Csz / 128, Msz / 128), 256, 0, stream>>>(
        h, Wqkv, nullptr, nullptr, QKVb, Msz, 3 * Csz, Csz, Csz, nullptr, nullptr, 0);
    attn_mfma<<<dim3(Bsz * Hsz, Tsz / 128), 256, 0, stream>>>(QKVb, AO);
    // x2 = x + AO @ Wo + bo -> d_out (fp32)
    gemm_bf16<<<dim3(Csz / 128, Msz / 128), 256, 0, stream>>>(
        AO, Wot, out, nullptr, nullptr, Msz, Csz, Csz, Csz, bo, x, 0);

    // --- FFN branch ---
    layernorm_bf16<<<Msz, 256, 0, stream>>>(out, ln2_g, ln2_b, h);
    gemm256<<<dim3(4 * Csz / 256, Msz / 256), 512, 0, stream>>>(
        h, W1t, nullptr, nullptr, ff1, Msz, 4 * Csz, Csz, Csz, b1, nullptr, 1, 0);
    // FFN2 split-K=2, ATOMIC epilogue: out already holds x2 (proj wrote it);
    // z=0 atomically adds ff1[:, :2048]@W2t^T + b2, z=1 adds the rest.
    // No p1 buffer, no add_partial pass.
    gemm256<<<dim3(Csz / 256, Msz / 256, 2), 512, 0, stream>>>(
        ff1, W2t, out, out, nullptr, Msz, Csz, 2 * Csz, 4 * Csz, b2, nullptr, 0, 1);
}